// Round 1
// baseline (11998.923 us; speedup 1.0000x reference)
//
#include <hip/hip_runtime.h>

// FPS: 2 batches x 131072 pts, 4096 samples/batch, seed = point 0.
// Persistent multi-block kernel: all coords+dists live in VGPRs.
// Per step: fused dist-update + local argmax -> packed u64 partial ->
// agent-scope slot store -> spin-poll all 32 slots -> global winner.
// Exact fp32 (no FMA contraction), first-index tiebreak to match jnp.argmax.

#define NB    32      // blocks per batch
#define TPB   256     // threads per block (4 waves)
#define PPT   16      // points per thread: NB*TPB*PPT = 131072
#define NPB   131072  // points per batch
#define MSAMP 4096    // samples per batch
#define RING  4       // slot ring depth (provable skew <= 2)
#define TAGM  0x7FFF

__global__ __launch_bounds__(TPB, 2)
void fps_kernel(const float4* __restrict__ pts, float* __restrict__ out,
                unsigned long long* __restrict__ slots)
{
#pragma clang fp contract(off)
  const int batch = blockIdx.x >> 5;        // / NB
  const int blk   = blockIdx.x & (NB - 1);
  const int tid   = threadIdx.x;
  const int lane  = tid & 63;
  const int wv    = tid >> 6;               // 0..3
  const float4* bpts = pts + (size_t)batch * NPB;
  unsigned long long* bslots = slots + (size_t)batch * (RING * NB);

  __shared__ unsigned long long s_part[TPB / 64];
  __shared__ float s_cur[4];

  const int base = blk * (TPB * PPT);       // block's first point (batch-local)

  // Register-resident coords + running min-dists.
  float px[PPT], py[PPT], pz[PPT], dist[PPT];
#pragma unroll
  for (int k = 0; k < PPT; ++k) {
    float4 p = bpts[base + k * TPB + tid];  // row = (b, x, y, z)
    px[k] = p.y; py[k] = p.z; pz[k] = p.w;
    dist[k] = __builtin_inff();             // min(inf, d) == d bit-exactly
  }

  if (tid == 0) {
    float4 c = bpts[0];                     // seed = local point 0
    s_cur[0] = c.x; s_cur[1] = c.y; s_cur[2] = c.z; s_cur[3] = c.w;
    if (blk == 0)
      *(float4*)(out + (size_t)batch * MSAMP * 4) = c;  // output row 0
  }
  __syncthreads();
  float sx = s_cur[1], sy = s_cur[2], sz = s_cur[3];

  for (int s = 1; s < MSAMP; ++s) {
    // ---- fused update + per-thread argmax (exact fp32, no contraction) ----
    float bestd = -1.0f; int besti = 0;
#pragma unroll
    for (int k = 0; k < PPT; ++k) {
      float dx = px[k] - sx, dy = py[k] - sy, dz = pz[k] - sz;
      float d2 = __fadd_rn(__fadd_rn(__fmul_rn(dx, dx), __fmul_rn(dy, dy)),
                           __fmul_rn(dz, dz));
      float nd = fminf(dist[k], d2);
      dist[k] = nd;
      // idx ascends with k => strict '>' keeps first max (jnp.argmax tiebreak)
      if (nd > bestd) { bestd = nd; besti = base + k * TPB + tid; }
    }

    // Pack (dist, step-tag, ~idx): u64 max == lexicographic (dist, -idx).
    unsigned long long pv =
        ((unsigned long long)__float_as_uint(bestd) << 32) |
        ((unsigned long long)(s & TAGM) << 17) |
        (unsigned long long)(0x1FFFF - besti);

    // ---- wave argmax (butterfly over 64 lanes) ----
#pragma unroll
    for (int m = 32; m >= 1; m >>= 1) {
      unsigned long long o = __shfl_xor(pv, m, 64);
      if (o > pv) pv = o;
    }
    if (lane == 0) s_part[wv] = pv;
    __syncthreads();

    if (wv == 0) {
      // ---- block argmax over 4 wave partials ----
      unsigned long long bv = (lane < (TPB / 64)) ? s_part[lane] : 0ull;
      {
        unsigned long long o = __shfl_xor(bv, 1, 64); if (o > bv) bv = o;
        o = __shfl_xor(bv, 2, 64);                    if (o > bv) bv = o;
      }
      if (lane == 0)
        __hip_atomic_store(&bslots[(s & (RING - 1)) * NB + blk], bv,
                           __ATOMIC_RELEASE, __HIP_MEMORY_SCOPE_AGENT);

      // ---- spin-poll all NB slots for this step (lanes 0..NB-1) ----
      unsigned long long w = 0;
      if (lane < NB) {
        unsigned long long* sp = &bslots[(s & (RING - 1)) * NB + lane];
        do {
          w = __hip_atomic_load(sp, __ATOMIC_ACQUIRE, __HIP_MEMORY_SCOPE_AGENT);
        } while (((unsigned)(w >> 17) & TAGM) != (unsigned)(s & TAGM));
      }
      // ---- cross-block argmax over 32 slot values ----
#pragma unroll
      for (int m = 16; m >= 1; m >>= 1) {
        unsigned long long o = __shfl_xor(w, m, 64);
        if (o > w) w = o;
      }
      if (lane == 0) {
        int widx = 0x1FFFF - (int)(w & 0x1FFFF);
        float4 c = bpts[widx];
        s_cur[0] = c.x; s_cur[1] = c.y; s_cur[2] = c.z; s_cur[3] = c.w;
        if (blk == 0)
          *(float4*)(out + (size_t)(batch * MSAMP + s) * 4) = c;
      }
    }
    __syncthreads();
    sx = s_cur[1]; sy = s_cur[2]; sz = s_cur[3];
  }
}

extern "C" void kernel_launch(void* const* d_in, const int* in_sizes, int n_in,
                              void* d_out, int out_size, void* d_ws, size_t ws_size,
                              hipStream_t stream) {
  const float4* pts = (const float4*)d_in[0];
  float* out = (float*)d_out;
  unsigned long long* slots = (unsigned long long*)d_ws;

  // Zero the slot ring (2 KB) so stale/poisoned tags can never validate.
  hipMemsetAsync(d_ws, 0, (size_t)2 * RING * NB * sizeof(unsigned long long),
                 stream);

  dim3 grid(2 * NB), block(TPB);
  hipLaunchKernelGGL(fps_kernel, grid, block, 0, stream, pts, out, slots);
}